// Round 7
// baseline (367.879 us; speedup 1.0000x reference)
//
#include <hip/hip_runtime.h>

// ---------------------------------------------------------------------------
// RGCN restructured: aggregate x[src] FIRST (per relation), then one GEMM
//   A = [Sn_rel0 | Sn_rel1 | x_self],  Wcat = [W0; W1; root]
// R4..R19: CSR counting sort, MFMA mm192, fused layer1/pool, pk accumulate.
// R20 (FAILED): 2x MLP on gather64 null -> gather path saturated (~3.4TB/s).
// R21 (361us): zero-row + staged signs + scalar loop control.
// R22 (FAILED): split-rel gather. R23 (FAILED): gather+GEMM LDS fusion.
// R24 (FAILED): k_l1 f32x2 halved loads-in-flight on an UNsaturated
//      latency-bound kernel (670GB/s, VALU 37%) -> regressed.
// R25 (BEST 353.6us): LDS-staged bucket-ordered k_part + LDS-staged k_csr.
// R26: (a) k_l1 e+=16 -> e+=32: 4 independent loads/lane in flight (R24's
//      inverse). k_l1 is the only kernel with slack on all counters.
//      (b) DIAGNOSTIC: gathers split into half-grids (~27us each) so next
//      top-5 exposes the hidden ~199us block (k_part/k_csr/mm192/gaps).
// ---------------------------------------------------------------------------

typedef unsigned int uint;
typedef unsigned short ushort;
typedef __attribute__((ext_vector_type(8))) short bf16x8;
typedef __attribute__((ext_vector_type(4))) float f32x4;
typedef __attribute__((ext_vector_type(2))) float f32x2;

#define EPB 6144   // edges per block in partition kernel; MUST be 6*1024
#define BCAP 8960  // fixed bucket capacity (256-node buckets)

__device__ __forceinline__ uint bf1(float f){          // f32 -> bf16 (RNE)
  uint u = __float_as_uint(f);
  return (u + 0x7fffu + ((u>>16)&1u)) >> 16;
}
__device__ __forceinline__ uint bfpack2(float lo, float hi){
  return bf1(lo) | (bf1(hi)<<16);
}
__device__ __forceinline__ f32x2 cvt2lo(uint w){   // bf16 pair -> f32x2
  f32x2 r; r.x = __uint_as_float(w<<16); r.y = __uint_as_float(w & 0xffff0000u);
  return r;
}
// reduce both components of an f32x2 across the 4 16-lane groups
__device__ __forceinline__ void red2(f32x2& a){
  a.x += __shfl_xor(a.x,16); a.x += __shfl_xor(a.x,32);
  a.y += __shfl_xor(a.y,16); a.y += __shfl_xor(a.y,32);
}
// accumulate one bf16x4 word-pair: tot += v; dif += sg*v. sg in {+1,-1}.
__device__ __forceinline__ void acc2(uint2 w, float sg,
    f32x2& tL, f32x2& tH, f32x2& dL, f32x2& dH){
  f32x2 lo = cvt2lo(w.x), hi = cvt2lo(w.y);
  f32x2 s2 = {sg, sg};
  tL += lo; tH += hi;
  dL += s2*lo; dH += s2*hi;
}

// --------------------- CSR build: fixed-region counting sort ---------------
// R25: single-read, LDS-staged, bucket-ordered output.
// bucket = dst>>8 (256 nodes); fixed region [b*BCAP, (b+1)*BCAP).
// bcur holds RELATIVE counts (memset-0 init); abs pos = b*BCAP + count.
// packed word: (src<<9)|((dst&255)<<1|ty)
__global__ __launch_bounds__(1024) void k_part(const int* __restrict__ ei,
    const int* __restrict__ et, int* __restrict__ bcur,
    uint* __restrict__ bk, int E, int NBK){
  __shared__ uint   stg[EPB];     // 24KB: bucket-sorted packed words
  __shared__ ushort stgb[EPB];    // 12KB: bucket tag per slot
  __shared__ int h[400];          // per-bucket counts (this block)
  __shared__ int basep[400];      // per-bucket absolute output base
  __shared__ int loc[400];        // per-bucket exclusive prefix (LDS slot)
  __shared__ int sc[512];         // scan workspace
  __shared__ int tot_s;
  int t = threadIdx.x;
  int base = blockIdx.x*EPB;

  // ---- load 6 edges/thread to registers (single global read) ----
  int e0=base+t,      e1=base+t+1024, e2=base+t+2048;
  int e3=base+t+3072, e4=base+t+4096, e5=base+t+5120;
  bool v0=e0<E, v1=e1<E, v2=e2<E, v3=e3<E, v4=e4<E, v5=e5<E;
  int s0=0,d0=0,y0=0,s1=0,d1=0,y1=0,s2=0,d2=0,y2=0;
  int s3=0,d3=0,y3=0,s4=0,d4=0,y4=0,s5=0,d5=0,y5=0;
  if (v0){ s0=ei[e0]; d0=ei[E+e0]; y0=et[e0]; }
  if (v1){ s1=ei[e1]; d1=ei[E+e1]; y1=et[e1]; }
  if (v2){ s2=ei[e2]; d2=ei[E+e2]; y2=et[e2]; }
  if (v3){ s3=ei[e3]; d3=ei[E+e3]; y3=et[e3]; }
  if (v4){ s4=ei[e4]; d4=ei[E+e4]; y4=et[e4]; }
  if (v5){ s5=ei[e5]; d5=ei[E+e5]; y5=et[e5]; }

  for (int i=t;i<NBK;i+=1024) h[i]=0;
  __syncthreads();
  // ---- histogram with rank capture ----
  int r0=0,r1=0,r2=0,r3=0,r4=0,r5=0;
  if (v0) r0 = atomicAdd(&h[d0>>8], 1);
  if (v1) r1 = atomicAdd(&h[d1>>8], 1);
  if (v2) r2 = atomicAdd(&h[d2>>8], 1);
  if (v3) r3 = atomicAdd(&h[d3>>8], 1);
  if (v4) r4 = atomicAdd(&h[d4>>8], 1);
  if (v5) r5 = atomicAdd(&h[d5>>8], 1);
  __syncthreads();
  // ---- inclusive scan over 512 (padded) bucket counts ----
  if (t < 512) sc[t] = (t < NBK) ? h[t] : 0;
  __syncthreads();
  for (int off=1; off<512; off<<=1){
    int v=0;
    if (t<512 && t>=off) v = sc[t-off];
    __syncthreads();
    if (t<512) sc[t] += v;
    __syncthreads();
  }
  // ---- per-bucket reservation + local base ----
  if (t < NBK){
    int c = h[t];
    basep[t] = c ? (t*BCAP + atomicAdd(&bcur[t], c)) : 0;
    loc[t]   = sc[t] - c;     // exclusive prefix
  }
  if (t == 511) tot_s = sc[511];
  __syncthreads();
  // ---- counting-sort into LDS ----
  if (v0){ int bu=d0>>8, p=loc[bu]+r0; stg[p]=((uint)s0<<9)|(uint)(((d0&255)<<1)|y0); stgb[p]=(ushort)bu; }
  if (v1){ int bu=d1>>8, p=loc[bu]+r1; stg[p]=((uint)s1<<9)|(uint)(((d1&255)<<1)|y1); stgb[p]=(ushort)bu; }
  if (v2){ int bu=d2>>8, p=loc[bu]+r2; stg[p]=((uint)s2<<9)|(uint)(((d2&255)<<1)|y2); stgb[p]=(ushort)bu; }
  if (v3){ int bu=d3>>8, p=loc[bu]+r3; stg[p]=((uint)s3<<9)|(uint)(((d3&255)<<1)|y3); stgb[p]=(ushort)bu; }
  if (v4){ int bu=d4>>8, p=loc[bu]+r4; stg[p]=((uint)s4<<9)|(uint)(((d4&255)<<1)|y4); stgb[p]=(ushort)bu; }
  if (v5){ int bu=d5>>8, p=loc[bu]+r5; stg[p]=((uint)s5<<9)|(uint)(((d5&255)<<1)|y5); stgb[p]=(ushort)bu; }
  __syncthreads();
  // ---- copy out: contiguous per-bucket runs ----
  int tot = tot_s;
  for (int i=t; i<tot; i+=1024){
    int bu  = stgb[i];
    int abs_ = basep[bu] + (i - loc[bu]);
    if (abs_ < (bu+1)*BCAP) bk[abs_] = stg[i];
  }
}

// per-bucket fine sort: 512 bins. R25: bucket window staged in LDS once.
// deg, pos (segment START), ssrc scatter confined to ~36KB bucket window.
// Blocks NBK..NBK+1 are tail blocks doing the weight pack (wt2/wt3),
// gp zeroing, and the h1/h2 ZERO ROW (row N).
__global__ __launch_bounds__(1024) void k_csr(const uint* __restrict__ bk,
    const int* __restrict__ bcur, int* __restrict__ deg,
    int* __restrict__ pos, int* __restrict__ ssrc, int N,
    const float* __restrict__ W2, const float* __restrict__ root2,
    const float* __restrict__ W3, const float* __restrict__ root3,
    ushort* __restrict__ wt2, ushort* __restrict__ wt3,
    float* __restrict__ gp, ushort* __restrict__ h1z,
    ushort* __restrict__ h2z, int NBK, int G){
  __shared__ uint stg[BCAP];     // 35.8KB bucket window
  __shared__ int h[512];
  __shared__ int cur[512];
  __shared__ int ws[256];
  int b = blockIdx.x, t = threadIdx.x;
  if (b >= NBK){
    const float* Wl = (b==NBK) ? W2 : W3;
    const float* rp = (b==NBK) ? root2 : root3;
    ushort* wt = (b==NBK) ? wt2 : wt3;
    for (int i=t; i<64*192; i+=1024){
      int n = i/192, k = i - n*192;
      float v = (k<128) ? Wl[k*64+n] : rp[(k-128)*64+n];
      wt[i] = (ushort)bf1(v);
    }
    if (b==NBK+1){
      for (int i=t;i<G*64;i+=1024) gp[i]=0.f;
      if (t < 64){                       // zero row N (gather zero-row trick)
        h1z[(size_t)N*64 + t] = 0;
        h2z[(size_t)N*64 + t] = 0;
      }
    }
    return;
  }
  int start = b*BCAP;
  int cnt = bcur[b]; if (cnt > BCAP) cnt = BCAP;
  if (t < 512) h[t]=0;
  for (int i=t; i<cnt; i+=1024) stg[i] = bk[start+i];
  __syncthreads();
  for (int i=t; i<cnt; i+=1024) atomicAdd(&h[stg[i]&511], 1);
  __syncthreads();
  int c0=0, c1=0, s=0;
  if (t < 256){
    c0=h[2*t]; c1=h[2*t+1]; s=c0+c1;
    ws[t] = s;
  }
  __syncthreads();
  for (int off=1; off<256; off<<=1){
    int tmp = (t>=off && t<256)? ws[t-off]:0;
    __syncthreads();
    if (t<256) ws[t] += tmp;
    __syncthreads();
  }
  if (t < 256){
    int base0 = start + ws[t] - s;
    cur[2*t]   = base0;
    cur[2*t+1] = base0 + c0;
    int node = (b<<8) + t;
    if (node < N){
      deg[(b<<9)+2*t]   = c0; deg[(b<<9)+2*t+1] = c1;
      pos[(b<<9)+2*t]   = base0; pos[(b<<9)+2*t+1] = base0 + c0;
    }
  }
  __syncthreads();
  for (int i=t; i<cnt; i+=1024){
    uint w = stg[i];
    int p = atomicAdd(&cur[w & 511], 1);
    ssrc[p] = (int)(w >> 9);
  }
}

// ----------------------- gather (64-ch bf16 features) ---------------------
// R21 version (best measured). R26: grid split via [n0, nEnd) (diagnostic).
__global__ __launch_bounds__(256) void k_gather64(
    const ushort* __restrict__ hp, const int* __restrict__ deg,
    const int* __restrict__ pos, const int* __restrict__ ssrc,
    ushort* __restrict__ sn, int nEnd, int n0, int NZ)
{
  int lane = threadIdx.x & 63;
  int wid  = (blockIdx.x*256 + threadIdx.x) >> 6;
  int c4 = lane & 15, eg = lane >> 4;
  int nA = n0 + wid*2, nB = nA+1;
  if (nA >= nEnd) return;
  int d0A = __builtin_amdgcn_readfirstlane(deg[2*nA]);
  int d1A = __builtin_amdgcn_readfirstlane(deg[2*nA+1]);
  int pA  = __builtin_amdgcn_readfirstlane(pos[2*nA]);
  int cA  = d0A + d1A;
  int d0B = 0, d1B = 0, pB = 0, cB = 0;
  if (nB < nEnd){
    d0B = __builtin_amdgcn_readfirstlane(deg[2*nB]);
    d1B = __builtin_amdgcn_readfirstlane(deg[2*nB+1]);
    pB  = __builtin_amdgcn_readfirstlane(pos[2*nB]);
    cB  = d0B+d1B;
  }

  f32x2 totAL={0,0}, totAH={0,0}, difAL={0,0}, difAH={0,0};
  f32x2 totBL={0,0}, totBH={0,0}, difBL={0,0}, difBH={0,0};
  int jA = 0, jB = 0;
  while (jA < cA || jB < cB){
    int tA = cA - jA; if (tA > 64) tA = 64;
    int tB = cB - jB; if (tB > 64) tB = 64;
    int r0A = d0A - jA, r0B = d0B - jB;     // rel0 remaining (scalar)
    // stage indices (invalid -> zero row NZ) and per-edge signs
    int svA = NZ, svB = NZ;
    if (lane < tA) svA = ssrc[pA + jA + lane];
    if (lane < tB) svB = ssrc[pB + jB + lane];
    float ssA = (lane < r0A) ? 1.f : -1.f;
    float ssB = (lane < r0B) ? 1.f : -1.f;
    int mt = tA > tB ? tA : tB;
    for (int e = 0; e < mt; e += 8){
      int i0 = e + eg, i1 = e + 4 + eg;
      int a0 = __shfl(svA, i0), b0 = __shfl(svB, i0);
      int a1 = __shfl(svA, i1), b1 = __shfl(svB, i1);
      float sA0 = __shfl(ssA, i0), sB0 = __shfl(ssB, i0);
      float sA1 = __shfl(ssA, i1), sB1 = __shfl(ssB, i1);
      // unconditional gathers; invalid edges hit the zeroed row NZ
      uint2 wA0 = *(const uint2*)(hp + (size_t)a0*64 + c4*4);
      uint2 wB0 = *(const uint2*)(hp + (size_t)b0*64 + c4*4);
      uint2 wA1 = *(const uint2*)(hp + (size_t)a1*64 + c4*4);
      uint2 wB1 = *(const uint2*)(hp + (size_t)b1*64 + c4*4);
      // per-accumulator order identical to R19: i0 then i1
      acc2(wA0, sA0, totAL, totAH, difAL, difAH);
      acc2(wB0, sB0, totBL, totBH, difBL, difBH);
      acc2(wA1, sA1, totAL, totAH, difAL, difAH);
      acc2(wB1, sB1, totBL, totBH, difBL, difBH);
    }
    jA += tA; jB += tB;
  }
  red2(totAL); red2(totAH); red2(difAL); red2(difAH);
  red2(totBL); red2(totBH); red2(difBL); red2(difBH);
  // lanes 0-15: (A,rel0) 16-31: (A,rel1) 32-47: (B,rel0) 48-63: (B,rel1)
  int rel = (lane >> 4) & 1;
  float4 tt_, dd_;
  if (lane < 32){
    tt_ = make_float4(totAL.x, totAL.y, totAH.x, totAH.y);
    dd_ = make_float4(difAL.x, difAL.y, difAH.x, difAH.y);
  } else {
    tt_ = make_float4(totBL.x, totBL.y, totBH.x, totBH.y);
    dd_ = make_float4(difBL.x, difBL.y, difBH.x, difBH.y);
  }
  int dsel = (lane < 32) ? (rel ? d1A : d0A) : (rel ? d1B : d0B);
  float sg = rel ? -1.f : 1.f;
  float id = 0.5f / (float)(dsel > 1 ? dsel : 1);
  float4 v;
  v.x = fmaf(sg, dd_.x, tt_.x) * id;
  v.y = fmaf(sg, dd_.y, tt_.y) * id;
  v.z = fmaf(sg, dd_.z, tt_.z) * id;
  v.w = fmaf(sg, dd_.w, tt_.w) * id;
  int n = (lane < 32) ? nA : nB;
  if (n < nEnd){
    uint2 pkt; pkt.x = bfpack2(v.x, v.y); pkt.y = bfpack2(v.z, v.w);
    *(uint2*)(sn + (size_t)n*128 + rel*64 + c4*4) = pkt;
  }
}

// --------------- layer 1 fused: gather (8-ch f32 x) + K=24 GEMM -----------
// R26: e+=32 unroll -> 4 independent loads/lane in flight (k_l1 is
// UNsaturated latency-bound: 670GB/s, VALU 37-56%, occ 71%). Accumulation
// order per accumulator is i0,i1,i2,i3 per 32-step (reordered sums,
// tolerance-fine). Scalar (readfirstlane) loop control.
__global__ __launch_bounds__(256) void k_l1(
    const float* __restrict__ xp, const int* __restrict__ deg,
    const int* __restrict__ pos, const int* __restrict__ ssrc,
    const float* __restrict__ W1,    // [2][8][64]
    const float* __restrict__ root1, // [8][64]
    const float* __restrict__ b1,    // [64]
    ushort* __restrict__ h1, int N)
{
  int lane = threadIdx.x & 63;
  int wid  = (blockIdx.x*256 + threadIdx.x) >> 6;
  int c = lane & 7, eg = lane >> 3;
  int nA = wid*2, nB = nA+1;
  if (nA >= N) return;
  int d0A = __builtin_amdgcn_readfirstlane(deg[2*nA]);
  int d1A = __builtin_amdgcn_readfirstlane(deg[2*nA+1]);
  int pA  = __builtin_amdgcn_readfirstlane(pos[2*nA]);
  int cA  = d0A + d1A;
  int d0B = 0, d1B = 0, pB = 0, cB = 0;
  if (nB < N){
    d0B = __builtin_amdgcn_readfirstlane(deg[2*nB]);
    d1B = __builtin_amdgcn_readfirstlane(deg[2*nB+1]);
    pB  = __builtin_amdgcn_readfirstlane(pos[2*nB]);
    cB  = d0B+d1B;
  }

  float totA=0.f, s1A=0.f, totB=0.f, s1B=0.f;
  int jA = 0, jB = 0;
  while (jA < cA || jB < cB){
    int tA = cA - jA; if (tA > 64) tA = 64;
    int tB = cB - jB; if (tB > 64) tB = 64;
    int svA = (lane < tA) ? ssrc[pA + jA + lane] : 0;
    int svB = (lane < tB) ? ssrc[pB + jB + lane] : 0;
    int mt = tA > tB ? tA : tB;
    for (int e = 0; e < mt; e += 32){
      int i0 = e + eg, i1 = e + 8 + eg, i2 = e + 16 + eg, i3 = e + 24 + eg;
      int a0 = __shfl(svA, i0), a1 = __shfl(svA, i1);
      int a2 = __shfl(svA, i2), a3 = __shfl(svA, i3);
      int b0 = __shfl(svB, i0), b1 = __shfl(svB, i1);
      int b2 = __shfl(svB, i2), b3 = __shfl(svB, i3);
      // 8 independent loads in flight
      float vA0 = xp[(size_t)a0*8 + c];
      float vA1 = xp[(size_t)a1*8 + c];
      float vA2 = xp[(size_t)a2*8 + c];
      float vA3 = xp[(size_t)a3*8 + c];
      float vB0 = xp[(size_t)b0*8 + c];
      float vB1 = xp[(size_t)b1*8 + c];
      float vB2 = xp[(size_t)b2*8 + c];
      float vB3 = xp[(size_t)b3*8 + c];
      vA0 = (i0 < tA) ? vA0 : 0.f;
      vA1 = (i1 < tA) ? vA1 : 0.f;
      vA2 = (i2 < tA) ? vA2 : 0.f;
      vA3 = (i3 < tA) ? vA3 : 0.f;
      vB0 = (i0 < tB) ? vB0 : 0.f;
      vB1 = (i1 < tB) ? vB1 : 0.f;
      vB2 = (i2 < tB) ? vB2 : 0.f;
      vB3 = (i3 < tB) ? vB3 : 0.f;
      totA += vA0;  s1A += ((jA + i0) >= d0A) ? vA0 : 0.f;
      totA += vA1;  s1A += ((jA + i1) >= d0A) ? vA1 : 0.f;
      totA += vA2;  s1A += ((jA + i2) >= d0A) ? vA2 : 0.f;
      totA += vA3;  s1A += ((jA + i3) >= d0A) ? vA3 : 0.f;
      totB += vB0;  s1B += ((jB + i0) >= d0B) ? vB0 : 0.f;
      totB += vB1;  s1B += ((jB + i1) >= d0B) ? vB1 : 0.f;
      totB += vB2;  s1B += ((jB + i2) >= d0B) ? vB2 : 0.f;
      totB += vB3;  s1B += ((jB + i3) >= d0B) ? vB3 : 0.f;
    }
    jA += tA; jB += tB;
  }
  float s0A = totA - s1A, s0B = totB - s1B;
  #pragma unroll
  for (int off=8; off<64; off<<=1){
    s0A += __shfl_xor(s0A, off); s1A += __shfl_xor(s1A, off);
    s0B += __shfl_xor(s0B, off); s1B += __shfl_xor(s1B, off);
  }
  s0A *= 1.f/(float)(d0A>1?d0A:1);  s1A *= 1.f/(float)(d1A>1?d1A:1);
  s0B *= 1.f/(float)(d0B>1?d0B:1);  s1B *= 1.f/(float)(d1B>1?d1B:1);

  // ---- K=24 GEMM in-wave: ch = lane; A values broadcast from lane k ----
  int ch = lane;
  float accA = b1[ch], accB = accA;
  #pragma unroll
  for (int k = 0; k < 8; ++k){
    float wv = W1[k*64 + ch];                 // rel0 row k
    accA = fmaf(__shfl(s0A, k), wv, accA);
    accB = fmaf(__shfl(s0B, k), wv, accB);
  }
  #pragma unroll
  for (int k = 0; k < 8; ++k){
    float wv = W1[512 + k*64 + ch];           // rel1 row k
    accA = fmaf(__shfl(s1A, k), wv, accA);
    accB = fmaf(__shfl(s1B, k), wv, accB);
  }
  #pragma unroll
  for (int k = 0; k < 8; ++k){
    float wr = root1[k*64 + ch];              // self row k
    float xa = xp[(size_t)nA*8 + k];          // wave-uniform scalar load
    accA = fmaf(xa, wr, accA);
    if (nB < N){
      float xb = xp[(size_t)nB*8 + k];
      accB = fmaf(xb, wr, accB);
    }
  }
  accA = fmaxf(accA, 0.f);
  h1[(size_t)nA*64 + ch] = (ushort)bf1(accA);
  if (nB < N){
    accB = fmaxf(accB, 0.f);
    h1[(size_t)nB*64 + ch] = (ushort)bf1(accB);
  }
}

// ----------------- GEMM layer 2 (K=192) via MFMA ---------------------------
template<int RELU, int OUTBF>
__global__ __launch_bounds__(256) void k_mm192m(
    const ushort* __restrict__ sn,   // [N,128] bf16 (rel0|rel1 means)
    const ushort* __restrict__ hp,   // [N,64]  bf16 self
    const ushort* __restrict__ wt,   // [64,192] bf16 = [Wcat]^T
    const float* __restrict__ bias, void* __restrict__ hout_, int N)
{
  int t = threadIdx.x, lane = t & 63, w = t >> 6;
  int quad = lane >> 4, l15 = lane & 15;
  int nb = blockIdx.x * 64;
  int node = nb + w*16 + l15;
  int ncl = node < N ? node : N-1;
  const ushort* arow_sn = sn + (size_t)ncl*128 + quad*8;
  const ushort* arow_hp = hp + (size_t)ncl*64  + quad*8;

  f32x4 acc0={0,0,0,0}, acc1={0,0,0,0}, acc2_={0,0,0,0}, acc3={0,0,0,0};
  #pragma unroll
  for (int ks = 0; ks < 6; ++ks){
    bf16x8 a = (ks < 4) ? *(const bf16x8*)(arow_sn + ks*32)
                        : *(const bf16x8*)(arow_hp + (ks-4)*32);
    const ushort* wk = wt + (size_t)l15*192 + ks*32 + quad*8;
    bf16x8 b0 = *(const bf16x8*)(wk);
    bf16x8 b1 = *(const bf16x8*)(wk + 16*192);
    bf16x8 b2 = *(const bf16x8*)(wk + 32*192);
    bf16x8 b3 = *(const bf16x8*)(wk + 48*192);
    acc0 = __builtin_amdgcn_mfma_f32_16x16x32_bf16(a, b0, acc0, 0,0,0);
    acc1 = __builtin_amdgcn_mfma_f32_16x16x32_bf16(a, b1, acc1, 0,0,0);
    acc2_ = __builtin_amdgcn_mfma_f32_16x16x32_bf16(a, b2, acc2_, 0,0,0);
    acc3 = __builtin_amdgcn_mfma_f32_16x16x32_bf16(a, b3, acc3, 0,0,0);
  }
  f32x4 accs[4] = {acc0, acc1, acc2_, acc3};
  #pragma unroll
  for (int tt = 0; tt < 4; ++tt){
    int n = tt*16 + l15;
    float bv = bias[n];
    #pragma unroll
    for (int i = 0; i < 4; ++i){
      int nd = nb + w*16 + quad*4 + i;
      if (nd < N){
        float v = accs[tt][i] + bv;
        if (RELU) v = fmaxf(v, 0.f);
        if (OUTBF) ((ushort*)hout_)[(size_t)nd*64 + n] = (ushort)bf1(v);
        else       ((float*)hout_)[(size_t)nd*64 + n] = v;
      }
    }
  }
}

// --------- GEMM layer 3 (K=192) + global_add_pool fused (atomicAdd) -------
__global__ __launch_bounds__(256) void k_mm192pool(
    const ushort* __restrict__ sn, const ushort* __restrict__ hp,
    const ushort* __restrict__ wt, const float* __restrict__ bias,
    const int* __restrict__ batch, float* __restrict__ gp, int N)
{
  __shared__ float hl[64*66];
  __shared__ int bl[64];
  int t = threadIdx.x, lane = t & 63, w = t >> 6;
  int quad = lane >> 4, l15 = lane & 15;
  int nb = blockIdx.x * 64;
  int node = nb + w*16 + l15;
  int ncl = node < N ? node : N-1;
  const ushort* arow_sn = sn + (size_t)ncl*128 + quad*8;
  const ushort* arow_hp = hp + (size_t)ncl*64  + quad*8;

  f32x4 acc0={0,0,0,0}, acc1={0,0,0,0}, acc2_={0,0,0,0}, acc3={0,0,0,0};
  #pragma unroll
  for (int ks = 0; ks < 6; ++ks){
    bf16x8 a = (ks < 4) ? *(const bf16x8*)(arow_sn + ks*32)
                        : *(const bf16x8*)(arow_hp + (ks-4)*32);
    const ushort* wk = wt + (size_t)l15*192 + ks*32 + quad*8;
    bf16x8 b0 = *(const bf16x8*)(wk);
    bf16x8 b1 = *(const bf16x8*)(wk + 16*192);
    bf16x8 b2 = *(const bf16x8*)(wk + 32*192);
    bf16x8 b3 = *(const bf16x8*)(wk + 48*192);
    acc0 = __builtin_amdgcn_mfma_f32_16x16x32_bf16(a, b0, acc0, 0,0,0);
    acc1 = __builtin_amdgcn_mfma_f32_16x16x32_bf16(a, b1, acc1, 0,0,0);
    acc2_ = __builtin_amdgcn_mfma_f32_16x16x32_bf16(a, b2, acc2_, 0,0,0);
    acc3 = __builtin_amdgcn_mfma_f32_16x16x32_bf16(a, b3, acc3, 0,0,0);
  }
  f32x4 accs[4] = {acc0, acc1, acc2_, acc3};
  #pragma unroll
  for (int tt = 0; tt < 4; ++tt){
    int ch = tt*16 + l15;
    float bv = bias[ch];
    #pragma unroll
    for (int i = 0; i < 4; ++i){
      int nl = w*16 + quad*4 + i;
      hl[nl*66 + ch] = accs[tt][i] + bv;
    }
  }
  if (t < 64) bl[t] = (nb + t < N) ? batch[nb + t] : -1;
  __syncthreads();
  int c = t & 63, q = t >> 6;
  float acc = 0.f; int curg = -1;
  #pragma unroll 4
  for (int i = 0; i < 16; ++i){
    int nl = q*16 + i;
    int g = bl[nl];
    if (g != curg){
      if (curg >= 0) atomicAdd(&gp[curg*64 + c], acc);
      curg = g; acc = 0.f;
    }
    if (g >= 0) acc += hl[nl*66 + c];
  }
  if (curg >= 0) atomicAdd(&gp[curg*64 + c], acc);
}

// ------------------------------- MLP head ---------------------------------
__global__ __launch_bounds__(256) void k_clf(const float* __restrict__ gp,
    const float* __restrict__ cW1, const float* __restrict__ cb1,
    const float* __restrict__ cW2, const float* __restrict__ cb2,
    float* __restrict__ out, int G){
  int lane = threadIdx.x & 63;
  int g = (blockIdx.x*256 + threadIdx.x) >> 6;
  if (g >= G) return;
  int j = lane & 31, half = lane >> 5;
  const float* gv = gp + (size_t)g*64 + half*32;
  const float* Wc = cW1 + half*32*32 + j;
  float s = 0.f;
  #pragma unroll 8
  for (int i=0;i<32;++i) s += gv[i] * Wc[i*32];
  s += __shfl_xor(s, 32);
  s = fmaxf(s + cb1[j], 0.f) * cW2[j];
  s += __shfl_xor(s, 1);  s += __shfl_xor(s, 2);
  s += __shfl_xor(s, 4);  s += __shfl_xor(s, 8);
  s += __shfl_xor(s, 16);
  if (lane == 0) out[g] = s + cb2[0];
}

extern "C" void kernel_launch(void* const* d_in, const int* in_sizes, int n_in,
                              void* d_out, int out_size, void* d_ws, size_t ws_size,
                              hipStream_t stream){
  const float* x     = (const float*)d_in[0];
  const int*   ei    = (const int*)d_in[1];
  const int*   et    = (const int*)d_in[2];
  const int*   batch = (const int*)d_in[3];
  const float* W1    = (const float*)d_in[4];
  const float* root1 = (const float*)d_in[5];
  const float* b1    = (const float*)d_in[6];
  const float* W2    = (const float*)d_in[7];
  const float* root2 = (const float*)d_in[8];
  const float* b2    = (const float*)d_in[9];
  const float* W3    = (const float*)d_in[10];
  const float* root3 = (const float*)d_in[11];
  const float* b3    = (const float*)d_in[12];
  const float* cW1   = (const float*)d_in[13];
  const float* cb1   = (const float*)d_in[14];
  const float* cW2   = (const float*)d_in[15];
  const float* cb2   = (const float*)d_in[16];
  float* out = (float*)d_out;
  (void)n_in; (void)ws_size;

  int N = in_sizes[0]/8;      // 100000
  int E = in_sizes[2];        // 3200000
  int G = out_size;           // 256
  int M = 2*N;
  int NBK = (N + 255) >> 8;   // 391 buckets of 256 nodes

  char* w = (char*)d_ws;
  auto alloc=[&](size_t bytes)->char*{ char* p=w; w += (bytes+255)&~(size_t)255; return p; };
  int*    bcur  = (int*)alloc(1024*4);
  int*    ssrc  = (int*)alloc((size_t)NBK*BCAP*4);  // 14.0 MB fixed regions
  int*    deg   = (int*)alloc((size_t)M*4);
  int*    pos   = (int*)alloc((size_t)M*4);
  ushort* h1    = (ushort*)alloc((size_t)(N+1)*64*2);  // +1: zero row N
  ushort* snU   = (ushort*)alloc((size_t)N*128*2); // 25.6 MB
  ushort* h2    = (ushort*)alloc((size_t)(N+1)*64*2);  // +1: zero row N
  float*  gp    = (float*)alloc((size_t)G*64*4);
  ushort* wt2   = (ushort*)alloc(64*192*2);
  ushort* wt3   = (ushort*)alloc(64*192*2);
  uint*   bk    = (uint*)snU;   // 14.0 MB < 25.6; dead before layer-2 gather writes snU

  hipMemsetAsync(bcur, 0, (size_t)NBK*4, stream);
  int nbE = (E + EPB - 1)/EPB;
  k_part <<<nbE,1024,0,stream>>>(ei,et,bcur,bk,E,NBK);
  k_csr  <<<NBK+2,1024,0,stream>>>(bk,bcur,deg,pos,ssrc,N,
                                   W2,root2,W3,root3,wt2,wt3,gp,h1,h2,NBK,G);

  // gather grid split: nodes [0, halfn) and [halfn, N) (diagnostic: halves
  // ~27us so rocprof top-5 exposes the hidden k_part/k_csr/mm192 block).
  int halfn = (((N+1)/2) + 1) & ~1;           // even split point
  if (halfn > N) halfn = N;
  int wv1 = (halfn+1)/2,      gb1 = (wv1+3)/4;
  int rem = N - halfn;
  int wv2 = (rem+1)/2,        gb2 = (rem > 0) ? (wv2+3)/4 : 0;
  int gb = (((N+1)/2) + 3) / 4;     // full grid (layer-1 only)
  int nbk = (N+63)/64;
  // layer 1 (gather + GEMM fused)
  k_l1<<<gb,256,0,stream>>>(x,deg,pos,ssrc,W1,root1,b1,h1,N);
  // layer 2
  k_gather64<<<gb1,256,0,stream>>>(h1,deg,pos,ssrc,snU,halfn,0,N);
  if (gb2 > 0)
    k_gather64<<<gb2,256,0,stream>>>(h1,deg,pos,ssrc,snU,N,halfn,N);
  k_mm192m<1,1><<<nbk,256,0,stream>>>(snU,h1,wt2,b2,h2,N);
  // layer 3 (GEMM + pool fused)
  k_gather64<<<gb1,256,0,stream>>>(h2,deg,pos,ssrc,snU,halfn,0,N);
  if (gb2 > 0)
    k_gather64<<<gb2,256,0,stream>>>(h2,deg,pos,ssrc,snU,N,halfn,N);
  k_mm192pool<<<nbk,256,0,stream>>>(snU,h2,wt3,b3,batch,gp,N);
  // head
  k_clf<<<(G*64+255)/256,256,0,stream>>>(gp,cW1,cb1,cW2,cb2,out,G);
}

// Round 8
// 350.267 us; speedup vs baseline: 1.0503x; 1.0503x over previous
//
#include <hip/hip_runtime.h>

// ---------------------------------------------------------------------------
// RGCN restructured: aggregate x[src] FIRST (per relation), then one GEMM
//   A = [Sn_rel0 | Sn_rel1 | x_self],  Wcat = [W0; W1; root]
// R4..R19: CSR counting sort, MFMA mm192, fused layer1/pool, pk accumulate.
// R20 (FAILED): 2x MLP on gather64 null -> gather path saturated (~3.4TB/s).
// R21 (361us): zero-row + staged signs + scalar loop control.
// R22 (FAILED): split-rel gather. R23 (FAILED): gather+GEMM LDS fusion.
// R24 (FAILED): k_l1 f32x2 (fewer loads in flight). R25 (BEST 353.6us):
//      LDS-staged bucket-ordered k_part + LDS-staged k_csr.
// R26: k_l1 e+=32 NULL (k_l1 insensitive to load depth AND valu cuts);
//      gather grid-split costs ~14us -> reverted.
// R27: cross-round arithmetic puts k_part+k_csr at ~95-115us combined
//      (each just under the 47us top-5 cutoff). Both are 16-wave blocks
//      whose prefix-scan runs a Hillis-Steele ladder with 18 (k_part) /
//      16 (k_csr) __syncthreads at ~2 blocks/CU residency -> barrier-
//      dominated. Replace with SINGLE-WAVE scan (wave 0: 8/4 counts per
//      lane serial + __shfl_up wave scan) = 2 barriers total; bucket
//      reservation concurrent on waves 1-6. Same values produced.
// ---------------------------------------------------------------------------

typedef unsigned int uint;
typedef unsigned short ushort;
typedef __attribute__((ext_vector_type(8))) short bf16x8;
typedef __attribute__((ext_vector_type(4))) float f32x4;
typedef __attribute__((ext_vector_type(2))) float f32x2;

#define EPB 6144   // edges per block in partition kernel; MUST be 6*1024
#define BCAP 8960  // fixed bucket capacity (256-node buckets)

__device__ __forceinline__ uint bf1(float f){          // f32 -> bf16 (RNE)
  uint u = __float_as_uint(f);
  return (u + 0x7fffu + ((u>>16)&1u)) >> 16;
}
__device__ __forceinline__ uint bfpack2(float lo, float hi){
  return bf1(lo) | (bf1(hi)<<16);
}
__device__ __forceinline__ f32x2 cvt2lo(uint w){   // bf16 pair -> f32x2
  f32x2 r; r.x = __uint_as_float(w<<16); r.y = __uint_as_float(w & 0xffff0000u);
  return r;
}
// reduce both components of an f32x2 across the 4 16-lane groups
__device__ __forceinline__ void red2(f32x2& a){
  a.x += __shfl_xor(a.x,16); a.x += __shfl_xor(a.x,32);
  a.y += __shfl_xor(a.y,16); a.y += __shfl_xor(a.y,32);
}
// accumulate one bf16x4 word-pair: tot += v; dif += sg*v. sg in {+1,-1}.
__device__ __forceinline__ void acc2(uint2 w, float sg,
    f32x2& tL, f32x2& tH, f32x2& dL, f32x2& dH){
  f32x2 lo = cvt2lo(w.x), hi = cvt2lo(w.y);
  f32x2 s2 = {sg, sg};
  tL += lo; tH += hi;
  dL += s2*lo; dH += s2*hi;
}

// --------------------- CSR build: fixed-region counting sort ---------------
// R25: single-read, LDS-staged, bucket-ordered output. R27: single-wave
// scan (2 barriers instead of 18).
// bucket = dst>>8 (256 nodes); fixed region [b*BCAP, (b+1)*BCAP).
// bcur holds RELATIVE counts (memset-0 init); abs pos = b*BCAP + count.
// packed word: (src<<9)|((dst&255)<<1|ty)
__global__ __launch_bounds__(1024) void k_part(const int* __restrict__ ei,
    const int* __restrict__ et, int* __restrict__ bcur,
    uint* __restrict__ bk, int E, int NBK){
  __shared__ uint   stg[EPB];     // 24KB: bucket-sorted packed words
  __shared__ ushort stgb[EPB];    // 12KB: bucket tag per slot
  __shared__ int h[400];          // per-bucket counts (this block)
  __shared__ int basep[400];      // per-bucket absolute output base
  __shared__ int loc[400];        // per-bucket exclusive prefix (LDS slot)
  __shared__ int tot_s;
  int t = threadIdx.x;
  int base = blockIdx.x*EPB;

  // ---- load 6 edges/thread to registers (single global read) ----
  int e0=base+t,      e1=base+t+1024, e2=base+t+2048;
  int e3=base+t+3072, e4=base+t+4096, e5=base+t+5120;
  bool v0=e0<E, v1=e1<E, v2=e2<E, v3=e3<E, v4=e4<E, v5=e5<E;
  int s0=0,d0=0,y0=0,s1=0,d1=0,y1=0,s2=0,d2=0,y2=0;
  int s3=0,d3=0,y3=0,s4=0,d4=0,y4=0,s5=0,d5=0,y5=0;
  if (v0){ s0=ei[e0]; d0=ei[E+e0]; y0=et[e0]; }
  if (v1){ s1=ei[e1]; d1=ei[E+e1]; y1=et[e1]; }
  if (v2){ s2=ei[e2]; d2=ei[E+e2]; y2=et[e2]; }
  if (v3){ s3=ei[e3]; d3=ei[E+e3]; y3=et[e3]; }
  if (v4){ s4=ei[e4]; d4=ei[E+e4]; y4=et[e4]; }
  if (v5){ s5=ei[e5]; d5=ei[E+e5]; y5=et[e5]; }

  for (int i=t;i<NBK;i+=1024) h[i]=0;
  __syncthreads();
  // ---- histogram with rank capture ----
  int r0=0,r1=0,r2=0,r3=0,r4=0,r5=0;
  if (v0) r0 = atomicAdd(&h[d0>>8], 1);
  if (v1) r1 = atomicAdd(&h[d1>>8], 1);
  if (v2) r2 = atomicAdd(&h[d2>>8], 1);
  if (v3) r3 = atomicAdd(&h[d3>>8], 1);
  if (v4) r4 = atomicAdd(&h[d4>>8], 1);
  if (v5) r5 = atomicAdd(&h[d5>>8], 1);
  __syncthreads();
  // ---- single-wave exclusive scan (wave 0); reservation on waves 1+ ----
  if (t < 64){
    int pre[8]; int s = 0;
    #pragma unroll
    for (int j=0;j<8;++j){
      int idx = t*8+j;
      int c = (idx < NBK) ? h[idx] : 0;
      pre[j] = s; s += c;
    }
    int run = s;
    #pragma unroll
    for (int off=1; off<64; off<<=1){
      int u = __shfl_up(run, off);
      if (t >= off) run += u;
    }
    int excl = run - s;
    #pragma unroll
    for (int j=0;j<8;++j){
      int idx = t*8+j;
      if (idx < NBK) loc[idx] = excl + pre[j];
    }
    if (t == 63) tot_s = run;
  } else if (t >= 64 && t < 64 + NBK){
    int bu = t - 64;
    int c = h[bu];
    basep[bu] = c ? (bu*BCAP + atomicAdd(&bcur[bu], c)) : 0;
  }
  __syncthreads();
  // ---- counting-sort into LDS ----
  if (v0){ int bu=d0>>8, p=loc[bu]+r0; stg[p]=((uint)s0<<9)|(uint)(((d0&255)<<1)|y0); stgb[p]=(ushort)bu; }
  if (v1){ int bu=d1>>8, p=loc[bu]+r1; stg[p]=((uint)s1<<9)|(uint)(((d1&255)<<1)|y1); stgb[p]=(ushort)bu; }
  if (v2){ int bu=d2>>8, p=loc[bu]+r2; stg[p]=((uint)s2<<9)|(uint)(((d2&255)<<1)|y2); stgb[p]=(ushort)bu; }
  if (v3){ int bu=d3>>8, p=loc[bu]+r3; stg[p]=((uint)s3<<9)|(uint)(((d3&255)<<1)|y3); stgb[p]=(ushort)bu; }
  if (v4){ int bu=d4>>8, p=loc[bu]+r4; stg[p]=((uint)s4<<9)|(uint)(((d4&255)<<1)|y4); stgb[p]=(ushort)bu; }
  if (v5){ int bu=d5>>8, p=loc[bu]+r5; stg[p]=((uint)s5<<9)|(uint)(((d5&255)<<1)|y5); stgb[p]=(ushort)bu; }
  __syncthreads();
  // ---- copy out: contiguous per-bucket runs ----
  int tot = tot_s;
  for (int i=t; i<tot; i+=1024){
    int bu  = stgb[i];
    int abs_ = basep[bu] + (i - loc[bu]);
    if (abs_ < (bu+1)*BCAP) bk[abs_] = stg[i];
  }
}

// per-bucket fine sort: 512 bins. R25: bucket window staged in LDS once.
// R27: single-wave scan (1 extra barrier instead of 16); wave 0 also
// writes deg/pos/cur. Blocks NBK..NBK+1 are tail blocks doing the weight
// pack (wt2/wt3), gp zeroing, and the h1/h2 ZERO ROW (row N).
__global__ __launch_bounds__(1024) void k_csr(const uint* __restrict__ bk,
    const int* __restrict__ bcur, int* __restrict__ deg,
    int* __restrict__ pos, int* __restrict__ ssrc, int N,
    const float* __restrict__ W2, const float* __restrict__ root2,
    const float* __restrict__ W3, const float* __restrict__ root3,
    ushort* __restrict__ wt2, ushort* __restrict__ wt3,
    float* __restrict__ gp, ushort* __restrict__ h1z,
    ushort* __restrict__ h2z, int NBK, int G){
  __shared__ uint stg[BCAP];     // 35.8KB bucket window
  __shared__ int h[512];
  __shared__ int cur[512];
  int b = blockIdx.x, t = threadIdx.x;
  if (b >= NBK){
    const float* Wl = (b==NBK) ? W2 : W3;
    const float* rp = (b==NBK) ? root2 : root3;
    ushort* wt = (b==NBK) ? wt2 : wt3;
    for (int i=t; i<64*192; i+=1024){
      int n = i/192, k = i - n*192;
      float v = (k<128) ? Wl[k*64+n] : rp[(k-128)*64+n];
      wt[i] = (ushort)bf1(v);
    }
    if (b==NBK+1){
      for (int i=t;i<G*64;i+=1024) gp[i]=0.f;
      if (t < 64){                       // zero row N (gather zero-row trick)
        h1z[(size_t)N*64 + t] = 0;
        h2z[(size_t)N*64 + t] = 0;
      }
    }
    return;
  }
  int start = b*BCAP;
  int cnt = bcur[b]; if (cnt > BCAP) cnt = BCAP;
  if (t < 512) h[t]=0;
  for (int i=t; i<cnt; i+=1024) stg[i] = bk[start+i];
  __syncthreads();
  for (int i=t; i<cnt; i+=1024) atomicAdd(&h[stg[i]&511], 1);
  __syncthreads();
  // ---- single-wave scan over 256 node-pair counts; writes cur/deg/pos ----
  if (t < 64){
    int c0v[4], c1v[4], pre[4]; int s = 0;
    #pragma unroll
    for (int j=0;j<4;++j){
      int idx = t*4+j;                 // node-pair index 0..255
      c0v[j] = h[2*idx]; c1v[j] = h[2*idx+1];
      pre[j] = s; s += c0v[j] + c1v[j];
    }
    int run = s;
    #pragma unroll
    for (int off=1; off<64; off<<=1){
      int u = __shfl_up(run, off);
      if (t >= off) run += u;
    }
    int excl = run - s;
    #pragma unroll
    for (int j=0;j<4;++j){
      int idx = t*4+j;
      int base0 = start + excl + pre[j];
      cur[2*idx]   = base0;
      cur[2*idx+1] = base0 + c0v[j];
      int node = (b<<8) + idx;
      if (node < N){
        deg[(b<<9)+2*idx]   = c0v[j]; deg[(b<<9)+2*idx+1] = c1v[j];
        pos[(b<<9)+2*idx]   = base0;  pos[(b<<9)+2*idx+1] = base0 + c0v[j];
      }
    }
  }
  __syncthreads();
  for (int i=t; i<cnt; i+=1024){
    uint w = stg[i];
    int p = atomicAdd(&cur[w & 511], 1);
    ssrc[p] = (int)(w >> 9);
  }
}

// ----------------------- gather (64-ch bf16 features) ---------------------
// R21 version (best measured): e+=8, 16-lane groups, zero-row unconditional
// loads, staged float signs broadcast via shfl, scalar loop control.
__global__ __launch_bounds__(256) void k_gather64(
    const ushort* __restrict__ hp, const int* __restrict__ deg,
    const int* __restrict__ pos, const int* __restrict__ ssrc,
    ushort* __restrict__ sn, int N)
{
  int lane = threadIdx.x & 63;
  int wid  = (blockIdx.x*256 + threadIdx.x) >> 6;
  int c4 = lane & 15, eg = lane >> 4;
  int nA = wid*2, nB = nA+1;
  if (nA >= N) return;
  int d0A = __builtin_amdgcn_readfirstlane(deg[2*nA]);
  int d1A = __builtin_amdgcn_readfirstlane(deg[2*nA+1]);
  int pA  = __builtin_amdgcn_readfirstlane(pos[2*nA]);
  int cA  = d0A + d1A;
  int d0B = 0, d1B = 0, pB = 0, cB = 0;
  if (nB < N){
    d0B = __builtin_amdgcn_readfirstlane(deg[2*nB]);
    d1B = __builtin_amdgcn_readfirstlane(deg[2*nB+1]);
    pB  = __builtin_amdgcn_readfirstlane(pos[2*nB]);
    cB  = d0B+d1B;
  }

  f32x2 totAL={0,0}, totAH={0,0}, difAL={0,0}, difAH={0,0};
  f32x2 totBL={0,0}, totBH={0,0}, difBL={0,0}, difBH={0,0};
  int jA = 0, jB = 0;
  while (jA < cA || jB < cB){
    int tA = cA - jA; if (tA > 64) tA = 64;
    int tB = cB - jB; if (tB > 64) tB = 64;
    int r0A = d0A - jA, r0B = d0B - jB;     // rel0 remaining (scalar)
    // stage indices (invalid -> zero row N) and per-edge signs
    int svA = N, svB = N;
    if (lane < tA) svA = ssrc[pA + jA + lane];
    if (lane < tB) svB = ssrc[pB + jB + lane];
    float ssA = (lane < r0A) ? 1.f : -1.f;
    float ssB = (lane < r0B) ? 1.f : -1.f;
    int mt = tA > tB ? tA : tB;
    for (int e = 0; e < mt; e += 8){
      int i0 = e + eg, i1 = e + 4 + eg;
      int a0 = __shfl(svA, i0), b0 = __shfl(svB, i0);
      int a1 = __shfl(svA, i1), b1 = __shfl(svB, i1);
      float sA0 = __shfl(ssA, i0), sB0 = __shfl(ssB, i0);
      float sA1 = __shfl(ssA, i1), sB1 = __shfl(ssB, i1);
      // unconditional gathers; invalid edges hit the zeroed row N
      uint2 wA0 = *(const uint2*)(hp + (size_t)a0*64 + c4*4);
      uint2 wB0 = *(const uint2*)(hp + (size_t)b0*64 + c4*4);
      uint2 wA1 = *(const uint2*)(hp + (size_t)a1*64 + c4*4);
      uint2 wB1 = *(const uint2*)(hp + (size_t)b1*64 + c4*4);
      // per-accumulator order identical to R19: i0 then i1
      acc2(wA0, sA0, totAL, totAH, difAL, difAH);
      acc2(wB0, sB0, totBL, totBH, difBL, difBH);
      acc2(wA1, sA1, totAL, totAH, difAL, difAH);
      acc2(wB1, sB1, totBL, totBH, difBL, difBH);
    }
    jA += tA; jB += tB;
  }
  red2(totAL); red2(totAH); red2(difAL); red2(difAH);
  red2(totBL); red2(totBH); red2(difBL); red2(difBH);
  // lanes 0-15: (A,rel0) 16-31: (A,rel1) 32-47: (B,rel0) 48-63: (B,rel1)
  int rel = (lane >> 4) & 1;
  float4 tt_, dd_;
  if (lane < 32){
    tt_ = make_float4(totAL.x, totAL.y, totAH.x, totAH.y);
    dd_ = make_float4(difAL.x, difAL.y, difAH.x, difAH.y);
  } else {
    tt_ = make_float4(totBL.x, totBL.y, totBH.x, totBH.y);
    dd_ = make_float4(difBL.x, difBL.y, difBH.x, difBH.y);
  }
  int dsel = (lane < 32) ? (rel ? d1A : d0A) : (rel ? d1B : d0B);
  float sg = rel ? -1.f : 1.f;
  float id = 0.5f / (float)(dsel > 1 ? dsel : 1);
  float4 v;
  v.x = fmaf(sg, dd_.x, tt_.x) * id;
  v.y = fmaf(sg, dd_.y, tt_.y) * id;
  v.z = fmaf(sg, dd_.z, tt_.z) * id;
  v.w = fmaf(sg, dd_.w, tt_.w) * id;
  int n = (lane < 32) ? nA : nB;
  if (n < N){
    uint2 pkt; pkt.x = bfpack2(v.x, v.y); pkt.y = bfpack2(v.z, v.w);
    *(uint2*)(sn + (size_t)n*128 + rel*64 + c4*4) = pkt;
  }
}

// --------------- layer 1 fused: gather (8-ch f32 x) + K=24 GEMM -----------
// R26 form (e+=32; measured identical to R18's 47us — kept).
__global__ __launch_bounds__(256) void k_l1(
    const float* __restrict__ xp, const int* __restrict__ deg,
    const int* __restrict__ pos, const int* __restrict__ ssrc,
    const float* __restrict__ W1,    // [2][8][64]
    const float* __restrict__ root1, // [8][64]
    const float* __restrict__ b1,    // [64]
    ushort* __restrict__ h1, int N)
{
  int lane = threadIdx.x & 63;
  int wid  = (blockIdx.x*256 + threadIdx.x) >> 6;
  int c = lane & 7, eg = lane >> 3;
  int nA = wid*2, nB = nA+1;
  if (nA >= N) return;
  int d0A = __builtin_amdgcn_readfirstlane(deg[2*nA]);
  int d1A = __builtin_amdgcn_readfirstlane(deg[2*nA+1]);
  int pA  = __builtin_amdgcn_readfirstlane(pos[2*nA]);
  int cA  = d0A + d1A;
  int d0B = 0, d1B = 0, pB = 0, cB = 0;
  if (nB < N){
    d0B = __builtin_amdgcn_readfirstlane(deg[2*nB]);
    d1B = __builtin_amdgcn_readfirstlane(deg[2*nB+1]);
    pB  = __builtin_amdgcn_readfirstlane(pos[2*nB]);
    cB  = d0B+d1B;
  }

  float totA=0.f, s1A=0.f, totB=0.f, s1B=0.f;
  int jA = 0, jB = 0;
  while (jA < cA || jB < cB){
    int tA = cA - jA; if (tA > 64) tA = 64;
    int tB = cB - jB; if (tB > 64) tB = 64;
    int svA = (lane < tA) ? ssrc[pA + jA + lane] : 0;
    int svB = (lane < tB) ? ssrc[pB + jB + lane] : 0;
    int mt = tA > tB ? tA : tB;
    for (int e = 0; e < mt; e += 32){
      int i0 = e + eg, i1 = e + 8 + eg, i2 = e + 16 + eg, i3 = e + 24 + eg;
      int a0 = __shfl(svA, i0), a1 = __shfl(svA, i1);
      int a2 = __shfl(svA, i2), a3 = __shfl(svA, i3);
      int b0 = __shfl(svB, i0), b1 = __shfl(svB, i1);
      int b2 = __shfl(svB, i2), b3 = __shfl(svB, i3);
      // 8 independent loads in flight
      float vA0 = xp[(size_t)a0*8 + c];
      float vA1 = xp[(size_t)a1*8 + c];
      float vA2 = xp[(size_t)a2*8 + c];
      float vA3 = xp[(size_t)a3*8 + c];
      float vB0 = xp[(size_t)b0*8 + c];
      float vB1 = xp[(size_t)b1*8 + c];
      float vB2 = xp[(size_t)b2*8 + c];
      float vB3 = xp[(size_t)b3*8 + c];
      vA0 = (i0 < tA) ? vA0 : 0.f;
      vA1 = (i1 < tA) ? vA1 : 0.f;
      vA2 = (i2 < tA) ? vA2 : 0.f;
      vA3 = (i3 < tA) ? vA3 : 0.f;
      vB0 = (i0 < tB) ? vB0 : 0.f;
      vB1 = (i1 < tB) ? vB1 : 0.f;
      vB2 = (i2 < tB) ? vB2 : 0.f;
      vB3 = (i3 < tB) ? vB3 : 0.f;
      totA += vA0;  s1A += ((jA + i0) >= d0A) ? vA0 : 0.f;
      totA += vA1;  s1A += ((jA + i1) >= d0A) ? vA1 : 0.f;
      totA += vA2;  s1A += ((jA + i2) >= d0A) ? vA2 : 0.f;
      totA += vA3;  s1A += ((jA + i3) >= d0A) ? vA3 : 0.f;
      totB += vB0;  s1B += ((jB + i0) >= d0B) ? vB0 : 0.f;
      totB += vB1;  s1B += ((jB + i1) >= d0B) ? vB1 : 0.f;
      totB += vB2;  s1B += ((jB + i2) >= d0B) ? vB2 : 0.f;
      totB += vB3;  s1B += ((jB + i3) >= d0B) ? vB3 : 0.f;
    }
    jA += tA; jB += tB;
  }
  float s0A = totA - s1A, s0B = totB - s1B;
  #pragma unroll
  for (int off=8; off<64; off<<=1){
    s0A += __shfl_xor(s0A, off); s1A += __shfl_xor(s1A, off);
    s0B += __shfl_xor(s0B, off); s1B += __shfl_xor(s1B, off);
  }
  s0A *= 1.f/(float)(d0A>1?d0A:1);  s1A *= 1.f/(float)(d1A>1?d1A:1);
  s0B *= 1.f/(float)(d0B>1?d0B:1);  s1B *= 1.f/(float)(d1B>1?d1B:1);

  // ---- K=24 GEMM in-wave: ch = lane; A values broadcast from lane k ----
  int ch = lane;
  float accA = b1[ch], accB = accA;
  #pragma unroll
  for (int k = 0; k < 8; ++k){
    float wv = W1[k*64 + ch];                 // rel0 row k
    accA = fmaf(__shfl(s0A, k), wv, accA);
    accB = fmaf(__shfl(s0B, k), wv, accB);
  }
  #pragma unroll
  for (int k = 0; k < 8; ++k){
    float wv = W1[512 + k*64 + ch];           // rel1 row k
    accA = fmaf(__shfl(s1A, k), wv, accA);
    accB = fmaf(__shfl(s1B, k), wv, accB);
  }
  #pragma unroll
  for (int k = 0; k < 8; ++k){
    float wr = root1[k*64 + ch];              // self row k
    float xa = xp[(size_t)nA*8 + k];          // wave-uniform scalar load
    accA = fmaf(xa, wr, accA);
    if (nB < N){
      float xb = xp[(size_t)nB*8 + k];
      accB = fmaf(xb, wr, accB);
    }
  }
  accA = fmaxf(accA, 0.f);
  h1[(size_t)nA*64 + ch] = (ushort)bf1(accA);
  if (nB < N){
    accB = fmaxf(accB, 0.f);
    h1[(size_t)nB*64 + ch] = (ushort)bf1(accB);
  }
}

// ----------------- GEMM layer 2 (K=192) via MFMA ---------------------------
template<int RELU, int OUTBF>
__global__ __launch_bounds__(256) void k_mm192m(
    const ushort* __restrict__ sn,   // [N,128] bf16 (rel0|rel1 means)
    const ushort* __restrict__ hp,   // [N,64]  bf16 self
    const ushort* __restrict__ wt,   // [64,192] bf16 = [Wcat]^T
    const float* __restrict__ bias, void* __restrict__ hout_, int N)
{
  int t = threadIdx.x, lane = t & 63, w = t >> 6;
  int quad = lane >> 4, l15 = lane & 15;
  int nb = blockIdx.x * 64;
  int node = nb + w*16 + l15;
  int ncl = node < N ? node : N-1;
  const ushort* arow_sn = sn + (size_t)ncl*128 + quad*8;
  const ushort* arow_hp = hp + (size_t)ncl*64  + quad*8;

  f32x4 acc0={0,0,0,0}, acc1={0,0,0,0}, acc2_={0,0,0,0}, acc3={0,0,0,0};
  #pragma unroll
  for (int ks = 0; ks < 6; ++ks){
    bf16x8 a = (ks < 4) ? *(const bf16x8*)(arow_sn + ks*32)
                        : *(const bf16x8*)(arow_hp + (ks-4)*32);
    const ushort* wk = wt + (size_t)l15*192 + ks*32 + quad*8;
    bf16x8 b0 = *(const bf16x8*)(wk);
    bf16x8 b1 = *(const bf16x8*)(wk + 16*192);
    bf16x8 b2 = *(const bf16x8*)(wk + 32*192);
    bf16x8 b3 = *(const bf16x8*)(wk + 48*192);
    acc0 = __builtin_amdgcn_mfma_f32_16x16x32_bf16(a, b0, acc0, 0,0,0);
    acc1 = __builtin_amdgcn_mfma_f32_16x16x32_bf16(a, b1, acc1, 0,0,0);
    acc2_ = __builtin_amdgcn_mfma_f32_16x16x32_bf16(a, b2, acc2_, 0,0,0);
    acc3 = __builtin_amdgcn_mfma_f32_16x16x32_bf16(a, b3, acc3, 0,0,0);
  }
  f32x4 accs[4] = {acc0, acc1, acc2_, acc3};
  #pragma unroll
  for (int tt = 0; tt < 4; ++tt){
    int n = tt*16 + l15;
    float bv = bias[n];
    #pragma unroll
    for (int i = 0; i < 4; ++i){
      int nd = nb + w*16 + quad*4 + i;
      if (nd < N){
        float v = accs[tt][i] + bv;
        if (RELU) v = fmaxf(v, 0.f);
        if (OUTBF) ((ushort*)hout_)[(size_t)nd*64 + n] = (ushort)bf1(v);
        else       ((float*)hout_)[(size_t)nd*64 + n] = v;
      }
    }
  }
}

// --------- GEMM layer 3 (K=192) + global_add_pool fused (atomicAdd) -------
__global__ __launch_bounds__(256) void k_mm192pool(
    const ushort* __restrict__ sn, const ushort* __restrict__ hp,
    const ushort* __restrict__ wt, const float* __restrict__ bias,
    const int* __restrict__ batch, float* __restrict__ gp, int N)
{
  __shared__ float hl[64*66];
  __shared__ int bl[64];
  int t = threadIdx.x, lane = t & 63, w = t >> 6;
  int quad = lane >> 4, l15 = lane & 15;
  int nb = blockIdx.x * 64;
  int node = nb + w*16 + l15;
  int ncl = node < N ? node : N-1;
  const ushort* arow_sn = sn + (size_t)ncl*128 + quad*8;
  const ushort* arow_hp = hp + (size_t)ncl*64  + quad*8;

  f32x4 acc0={0,0,0,0}, acc1={0,0,0,0}, acc2_={0,0,0,0}, acc3={0,0,0,0};
  #pragma unroll
  for (int ks = 0; ks < 6; ++ks){
    bf16x8 a = (ks < 4) ? *(const bf16x8*)(arow_sn + ks*32)
                        : *(const bf16x8*)(arow_hp + (ks-4)*32);
    const ushort* wk = wt + (size_t)l15*192 + ks*32 + quad*8;
    bf16x8 b0 = *(const bf16x8*)(wk);
    bf16x8 b1 = *(const bf16x8*)(wk + 16*192);
    bf16x8 b2 = *(const bf16x8*)(wk + 32*192);
    bf16x8 b3 = *(const bf16x8*)(wk + 48*192);
    acc0 = __builtin_amdgcn_mfma_f32_16x16x32_bf16(a, b0, acc0, 0,0,0);
    acc1 = __builtin_amdgcn_mfma_f32_16x16x32_bf16(a, b1, acc1, 0,0,0);
    acc2_ = __builtin_amdgcn_mfma_f32_16x16x32_bf16(a, b2, acc2_, 0,0,0);
    acc3 = __builtin_amdgcn_mfma_f32_16x16x32_bf16(a, b3, acc3, 0,0,0);
  }
  f32x4 accs[4] = {acc0, acc1, acc2_, acc3};
  #pragma unroll
  for (int tt = 0; tt < 4; ++tt){
    int ch = tt*16 + l15;
    float bv = bias[ch];
    #pragma unroll
    for (int i = 0; i < 4; ++i){
      int nl = w*16 + quad*4 + i;
      hl[nl*66 + ch] = accs[tt][i] + bv;
    }
  }
  if (t < 64) bl[t] = (nb + t < N) ? batch[nb + t] : -1;
  __syncthreads();
  int c = t & 63, q = t >> 6;
  float acc = 0.f; int curg = -1;
  #pragma unroll 4
  for (int i = 0; i < 16; ++i){
    int nl = q*16 + i;
    int g = bl[nl];
    if (g != curg){
      if (curg >= 0) atomicAdd(&gp[curg*64 + c], acc);
      curg = g; acc = 0.f;
    }
    if (g >= 0) acc += hl[nl*66 + c];
  }
  if (curg >= 0) atomicAdd(&gp[curg*64 + c], acc);
}

// ------------------------------- MLP head ---------------------------------
__global__ __launch_bounds__(256) void k_clf(const float* __restrict__ gp,
    const float* __restrict__ cW1, const float* __restrict__ cb1,
    const float* __restrict__ cW2, const float* __restrict__ cb2,
    float* __restrict__ out, int G){
  int lane = threadIdx.x & 63;
  int g = (blockIdx.x*256 + threadIdx.x) >> 6;
  if (g >= G) return;
  int j = lane & 31, half = lane >> 5;
  const float* gv = gp + (size_t)g*64 + half*32;
  const float* Wc = cW1 + half*32*32 + j;
  float s = 0.f;
  #pragma unroll 8
  for (int i=0;i<32;++i) s += gv[i] * Wc[i*32];
  s += __shfl_xor(s, 32);
  s = fmaxf(s + cb1[j], 0.f) * cW2[j];
  s += __shfl_xor(s, 1);  s += __shfl_xor(s, 2);
  s += __shfl_xor(s, 4);  s += __shfl_xor(s, 8);
  s += __shfl_xor(s, 16);
  if (lane == 0) out[g] = s + cb2[0];
}

extern "C" void kernel_launch(void* const* d_in, const int* in_sizes, int n_in,
                              void* d_out, int out_size, void* d_ws, size_t ws_size,
                              hipStream_t stream){
  const float* x     = (const float*)d_in[0];
  const int*   ei    = (const int*)d_in[1];
  const int*   et    = (const int*)d_in[2];
  const int*   batch = (const int*)d_in[3];
  const float* W1    = (const float*)d_in[4];
  const float* root1 = (const float*)d_in[5];
  const float* b1    = (const float*)d_in[6];
  const float* W2    = (const float*)d_in[7];
  const float* root2 = (const float*)d_in[8];
  const float* b2    = (const float*)d_in[9];
  const float* W3    = (const float*)d_in[10];
  const float* root3 = (const float*)d_in[11];
  const float* b3    = (const float*)d_in[12];
  const float* cW1   = (const float*)d_in[13];
  const float* cb1   = (const float*)d_in[14];
  const float* cW2   = (const float*)d_in[15];
  const float* cb2   = (const float*)d_in[16];
  float* out = (float*)d_out;
  (void)n_in; (void)ws_size;

  int N = in_sizes[0]/8;      // 100000
  int E = in_sizes[2];        // 3200000
  int G = out_size;           // 256
  int M = 2*N;
  int NBK = (N + 255) >> 8;   // 391 buckets of 256 nodes

  char* w = (char*)d_ws;
  auto alloc=[&](size_t bytes)->char*{ char* p=w; w += (bytes+255)&~(size_t)255; return p; };
  int*    bcur  = (int*)alloc(1024*4);
  int*    ssrc  = (int*)alloc((size_t)NBK*BCAP*4);  // 14.0 MB fixed regions
  int*    deg   = (int*)alloc((size_t)M*4);
  int*    pos   = (int*)alloc((size_t)M*4);
  ushort* h1    = (ushort*)alloc((size_t)(N+1)*64*2);  // +1: zero row N
  ushort* snU   = (ushort*)alloc((size_t)N*128*2); // 25.6 MB
  ushort* h2    = (ushort*)alloc((size_t)(N+1)*64*2);  // +1: zero row N
  float*  gp    = (float*)alloc((size_t)G*64*4);
  ushort* wt2   = (ushort*)alloc(64*192*2);
  ushort* wt3   = (ushort*)alloc(64*192*2);
  uint*   bk    = (uint*)snU;   // 14.0 MB < 25.6; dead before layer-2 gather writes snU

  hipMemsetAsync(bcur, 0, (size_t)NBK*4, stream);
  int nbE = (E + EPB - 1)/EPB;
  k_part <<<nbE,1024,0,stream>>>(ei,et,bcur,bk,E,NBK);
  k_csr  <<<NBK+2,1024,0,stream>>>(bk,bcur,deg,pos,ssrc,N,
                                   W2,root2,W3,root3,wt2,wt3,gp,h1,h2,NBK,G);

  int gb = (((N+1)/2) + 3) / 4;     // waves = ceil(N/2), 4 waves/block
  int nbk = (N+63)/64;
  // layer 1 (gather + GEMM fused)
  k_l1<<<gb,256,0,stream>>>(x,deg,pos,ssrc,W1,root1,b1,h1,N);
  // layer 2
  k_gather64<<<gb,256,0,stream>>>(h1,deg,pos,ssrc,snU,N);
  k_mm192m<1,1><<<nbk,256,0,stream>>>(snU,h1,wt2,b2,h2,N);
  // layer 3 (GEMM + pool fused)
  k_gather64<<<gb,256,0,stream>>>(h2,deg,pos,ssrc,snU,N);
  k_mm192pool<<<nbk,256,0,stream>>>(snU,h2,wt3,b3,batch,gp,N);
  // head
  k_clf<<<(G*64+255)/256,256,0,stream>>>(gp,cW1,cb1,cW2,cb2,out,G);
}